// Round 3
// baseline (49.079 us; speedup 1.0000x reference)
//
#include <hip/hip_runtime.h>
#include <math.h>

// N=16384, D=64, C=64.
// loss = 1 - (1/n_unique) * sum_c [ (||S_c||^2 - n_c) / (n_c (n_c - 1)) ]
// where S_c = sum of row-normalized features of class c.
//
// 2 dispatches, no global atomics, no workspace zeroing:
//   phase1: 64 blocks x 1024 thr, block-local LDS accumulate, write partials
//   finish: 1 block x 1024 thr, parallel-reduce 64 partials, emit scalar.

#define NCLS 64
#define DIM 64
#define NB 64                      // phase1 blocks
#define ROWS_PER_BLOCK 256         // 16384 / NB
#define P1_THREADS 1024

__global__ __launch_bounds__(P1_THREADS) void cpl_phase1(
    const float* __restrict__ feat,   // [n, DIM]
    const int* __restrict__ pred,     // [n]
    float* __restrict__ partial,      // [NB, NCLS*DIM]
    float* __restrict__ cntp,         // [NB, NCLS]
    int n)
{
    __shared__ float s_acc[NCLS * DIM];
    __shared__ float s_cnt[NCLS];
    const int tid = threadIdx.x;

    for (int i = tid; i < NCLS * DIM; i += P1_THREADS) s_acc[i] = 0.0f;
    if (tid < NCLS) s_cnt[tid] = 0.0f;
    __syncthreads();

    const int lane = tid & 63;
    const int wave = tid >> 6;                               // 0..15
    const int rows_per_wave = ROWS_PER_BLOCK / (P1_THREADS / 64);  // 16
    const int row0 = blockIdx.x * ROWS_PER_BLOCK + wave * rows_per_wave;

    for (int r = row0; r < row0 + rows_per_wave; ++r) {
        if (r >= n) break;
        float x = feat[(size_t)r * DIM + lane];              // coalesced
        float s = x * x;
        #pragma unroll
        for (int off = 32; off; off >>= 1) s += __shfl_xor(s, off, 64);
        float v = x / sqrtf(s);                              // normalized
        int c = pred[r];                                     // wave-uniform
        atomicAdd(&s_acc[c * DIM + lane], v);                // LDS, 2-way/bank
        if (lane == 0) atomicAdd(&s_cnt[c], 1.0f);
    }
    __syncthreads();

    // Block-private slots: fully written each call, no init required.
    float* p = partial + (size_t)blockIdx.x * (NCLS * DIM);
    for (int i = tid; i < NCLS * DIM; i += P1_THREADS) p[i] = s_acc[i];
    if (tid < NCLS) cntp[blockIdx.x * NCLS + tid] = s_cnt[tid];
}

__global__ __launch_bounds__(1024) void cpl_finish(
    const float* __restrict__ partial,  // [NB, NCLS*DIM]
    const float* __restrict__ cntp,     // [NB, NCLS]
    float* __restrict__ out)            // [1]
{
    __shared__ float s_tot[NCLS][DIM + 1];   // +1 pad
    __shared__ float s_cnt[NCLS];
    __shared__ float s_avg[NCLS];
    __shared__ float s_pres[NCLS];
    const int t = threadIdx.x;

    // Class counts: wave 0, lane=class, 64 coalesced 256B loads.
    if (t < NCLS) {
        float c = 0.0f;
        #pragma unroll 8
        for (int b = 0; b < NB; ++b) c += cntp[b * NCLS + t];
        s_cnt[t] = c;
    }
    // Class vectors: 4096 idx over 1024 threads -> 4 idx/thread, 64 partials.
    for (int idx = t; idx < NCLS * DIM; idx += 1024) {
        float s = 0.0f;
        #pragma unroll 8
        for (int b = 0; b < NB; ++b) s += partial[(size_t)b * (NCLS * DIM) + idx];
        s_tot[idx >> 6][idx & 63] = s;
    }
    __syncthreads();

    // ||S_c||^2: 16 threads per class (contiguous in-wave), shfl reduce.
    const int c = t >> 4;
    const int p = t & 15;
    float s = 0.0f;
    #pragma unroll
    for (int k = 0; k < 4; ++k) {
        float v = s_tot[c][p * 4 + k];
        s += v * v;
    }
    s += __shfl_xor(s, 1, 64);
    s += __shfl_xor(s, 2, 64);
    s += __shfl_xor(s, 4, 64);
    s += __shfl_xor(s, 8, 64);
    if (p == 0) {
        float nc = s_cnt[c];
        s_avg[c]  = (nc > 1.5f) ? (s - nc) / (nc * (nc - 1.0f)) : 0.0f;
        s_pres[c] = (nc > 0.5f) ? 1.0f : 0.0f;
    }
    __syncthreads();

    if (t < 64) {
        float a = s_avg[t];
        float pr = s_pres[t];
        #pragma unroll
        for (int off = 32; off; off >>= 1) {
            a  += __shfl_xor(a, off, 64);
            pr += __shfl_xor(pr, off, 64);
        }
        if (t == 0) out[0] = 1.0f - a / pr;
    }
}

extern "C" void kernel_launch(void* const* d_in, const int* in_sizes, int n_in,
                              void* d_out, int out_size, void* d_ws, size_t ws_size,
                              hipStream_t stream) {
    const float* feat = (const float*)d_in[0];
    const int*   pred = (const int*)d_in[1];
    float* out = (float*)d_out;

    const int n = in_sizes[1];   // 16384

    float* partial = (float*)d_ws;                       // NB * 4096 floats
    float* cntp    = partial + (size_t)NB * (NCLS * DIM); // NB * 64 floats

    cpl_phase1<<<NB, P1_THREADS, 0, stream>>>(feat, pred, partial, cntp, n);
    cpl_finish<<<1, 1024, 0, stream>>>(partial, cntp, out);
}